// Round 1
// baseline (679.949 us; speedup 1.0000x reference)
//
#include <hip/hip_runtime.h>
#include <hip/hip_bf16.h>
#include <math.h>

// ---------------------------------------------------------------------------
// Kernel 1: int4 symmetric per-tensor weight quantization (Brevitas-style).
//   scale = max|W| / 7 ;  Wq = clip(rint(W/scale), -8, 7) * scale
// Writes Wq TRANSPOSED into ws as [2048][4] floats so the main kernel can
// fetch all 4 output-channels' weights for a feature with one float4 load.
// Must run every launch: d_ws is re-poisoned before each timed call.
// ---------------------------------------------------------------------------
__global__ void quant_w_kernel(const float* __restrict__ W,
                               float* __restrict__ wqt /* [2048][4] */) {
    __shared__ float smax[4];
    const int t = threadIdx.x;           // 0..255
    float m = 0.0f;
    for (int i = t; i < 4 * 2048; i += 256) m = fmaxf(m, fabsf(W[i]));
    #pragma unroll
    for (int off = 32; off; off >>= 1) m = fmaxf(m, __shfl_down(m, off));
    if ((t & 63) == 0) smax[t >> 6] = m;
    __syncthreads();
    const float M = fmaxf(fmaxf(smax[0], smax[1]), fmaxf(smax[2], smax[3]));
    const float scale = M / 7.0f;
    for (int i = t; i < 4 * 2048; i += 256) {
        float w = W[i];
        float q = rintf(w / scale);               // numpy round: half-to-even
        q = fminf(fmaxf(q, -8.0f), 7.0f);
        const int o = i >> 11;                    // output channel 0..3
        const int f = i & 2047;                   // feature
        wqt[f * 4 + o] = q * scale;
    }
}

// ---------------------------------------------------------------------------
// Kernel 2: fused maxpool(2^3) + linear(2048->4) + bias + softmax.
// One block per batch item. 256 threads; each thread owns 4 window-groups.
// A window-group = (c, dp, hp, q): four float4 loads (d0/d1 x h0/h1, same
// 16B quarter-row q) that form the complete 2x2x2 footprints of pooled
// features wp = 2q and 2q+1. No cross-thread pooling communication.
// ---------------------------------------------------------------------------
__global__ __launch_bounds__(256) void fused_pool_linear_softmax(
        const float* __restrict__ x,     // [8192][4][16][16][16]
        const float* __restrict__ wqt,   // [2048][4]
        const float* __restrict__ bias,  // [4]
        float* __restrict__ out) {       // [8192][4]
    const int b = blockIdx.x;
    const float* __restrict__ xb = x + (size_t)b * 16384;
    const int t = threadIdx.x;

    float4 acc = make_float4(0.f, 0.f, 0.f, 0.f);

    #pragma unroll
    for (int it = 0; it < 4; ++it) {
        const int G  = t + 256 * it;     // 0..1023 group id
        const int q  = G & 3;            // quarter-row (w bundle of 4)
        const int hp = (G >> 2) & 7;     // pooled h
        const int dp = (G >> 5) & 7;     // pooled d
        const int c  = G >> 8;           // channel
        const int base = c * 4096 + (dp << 1) * 256 + (hp << 1) * 16 + (q << 2);

        const float4 v00 = *(const float4*)(xb + base);          // d0,h0
        const float4 v01 = *(const float4*)(xb + base + 16);     // d0,h1
        const float4 v10 = *(const float4*)(xb + base + 256);    // d1,h0
        const float4 v11 = *(const float4*)(xb + base + 272);    // d1,h1

        const float p0 = fmaxf(fmaxf(fmaxf(v00.x, v00.y), fmaxf(v01.x, v01.y)),
                               fmaxf(fmaxf(v10.x, v10.y), fmaxf(v11.x, v11.y)));
        const float p1 = fmaxf(fmaxf(fmaxf(v00.z, v00.w), fmaxf(v01.z, v01.w)),
                               fmaxf(fmaxf(v10.z, v10.w), fmaxf(v11.z, v11.w)));

        const int f0 = c * 512 + dp * 64 + hp * 8 + (q << 1);
        const float4 w0 = *(const float4*)(wqt + f0 * 4);
        const float4 w1 = *(const float4*)(wqt + (f0 + 1) * 4);

        acc.x += p0 * w0.x + p1 * w1.x;
        acc.y += p0 * w0.y + p1 * w1.y;
        acc.z += p0 * w0.z + p1 * w1.z;
        acc.w += p0 * w0.w + p1 * w1.w;
    }

    // wave (64-lane) shuffle reduction of the 4 accumulators
    #pragma unroll
    for (int off = 32; off; off >>= 1) {
        acc.x += __shfl_down(acc.x, off);
        acc.y += __shfl_down(acc.y, off);
        acc.z += __shfl_down(acc.z, off);
        acc.w += __shfl_down(acc.w, off);
    }

    __shared__ float4 red[4];
    const int wave = t >> 6;
    if ((t & 63) == 0) red[wave] = acc;
    __syncthreads();

    if (t == 0) {
        float l0 = red[0].x + red[1].x + red[2].x + red[3].x + bias[0];
        float l1 = red[0].y + red[1].y + red[2].y + red[3].y + bias[1];
        float l2 = red[0].z + red[1].z + red[2].z + red[3].z + bias[2];
        float l3 = red[0].w + red[1].w + red[2].w + red[3].w + bias[3];
        const float m  = fmaxf(fmaxf(l0, l1), fmaxf(l2, l3));
        const float e0 = expf(l0 - m), e1 = expf(l1 - m),
                    e2 = expf(l2 - m), e3 = expf(l3 - m);
        const float inv = 1.0f / (e0 + e1 + e2 + e3);
        *(float4*)(out + (size_t)b * 4) =
            make_float4(e0 * inv, e1 * inv, e2 * inv, e3 * inv);
    }
}

extern "C" void kernel_launch(void* const* d_in, const int* in_sizes, int n_in,
                              void* d_out, int out_size, void* d_ws, size_t ws_size,
                              hipStream_t stream) {
    const float* x    = (const float*)d_in[0];   // [8192,4,16,16,16]
    const float* W    = (const float*)d_in[1];   // [4,2048]
    const float* bias = (const float*)d_in[2];   // [4]
    float* out = (float*)d_out;                  // [8192,4]
    float* wqt = (float*)d_ws;                   // [2048][4] quantized W^T

    quant_w_kernel<<<1, 256, 0, stream>>>(W, wqt);
    fused_pool_linear_softmax<<<8192, 256, 0, stream>>>(x, wqt, bias, out);
}